// Round 14
// baseline (184.204 us; speedup 1.0000x reference)
//
#include <hip/hip_runtime.h>

#define NK3 30  // 3*K columns per node
#define NKP 15  // float2 pairs per row

// MEASUREMENT ROUND: reps=10 inner loops make each kernel visible in rocprof
// top-5 (fills sit at ~70us). Bodies are idempotent => correctness preserved.

__device__ __forceinline__ float hw_log2(float a) { return __builtin_amdgcn_logf(a); }
__device__ __forceinline__ float hw_exp2(float a) { return __builtin_amdgcn_exp2f(a); }
__device__ __forceinline__ float hw_rcp(float a)  { return __builtin_amdgcn_rcpf(a); }

template <int CTRL>
__device__ __forceinline__ float dpp_add(float v) {
    int s = __builtin_amdgcn_update_dpp(0, __float_as_int(v), CTRL, 0xF, 0xF, true);
    return v + __int_as_float(s);
}
__device__ __forceinline__ float group16_sum(float v) {
    v = dpp_add<0xB1>(v);
    v = dpp_add<0x4E>(v);
    v = dpp_add<0x141>(v);
    v = dpp_add<0x140>(v);
    return v;
}

// ---------------- K1 (x reps) ----------------
__global__ __launch_bounds__(256) void k1_window_sums(
    const float* __restrict__ x, const float* __restrict__ uniforms,
    float* __restrict__ wp16, int N, int reps)
{
    const int w    = (blockIdx.x << 2) + (threadIdx.x >> 6);
    const int lane = threadIdx.x & 63;
    const int base = w << 6;
    if (base >= N) return;

    for (int rep = 0; rep < reps; ++rep) {
        const int n  = base + lane;
        const int nv = (n < N) ? n : (N - 1);

        const float2* row = reinterpret_cast<const float2*>(uniforms + (size_t)nv * NK3);
        float2 u[NKP];
#pragma unroll
        for (int k = 0; k < NKP; ++k) u[k] = row[k];
        float E = hw_exp2(x[nv] * 1.44269504f);
        E = (n < N) ? E : 0.0f;

        float r[NK3];
#pragma unroll
        for (int k = 0; k < NKP; ++k) {
            r[2 * k]     = E * hw_rcp(-hw_log2(u[k].x));
            r[2 * k + 1] = E * hw_rcp(-hw_log2(u[k].y));
        }

#pragma unroll
        for (int j = 0; j < NK3; ++j) r[j] = group16_sum(r[j]);

        if ((lane & 15) == 0) {
            float* dst = wp16 + ((size_t)(base >> 4) + (lane >> 4)) * NK3;
#pragma unroll
            for (int j = 0; j < NK3; ++j) dst[j] = r[j];
        }
    }
}

// ---------------- K2 (x reps) ----------------
__global__ __launch_bounds__(256) void k2_segment_den(
    const float* __restrict__ x, const float* __restrict__ uniforms,
    const int* __restrict__ ptr, const float* __restrict__ wp16,
    float* __restrict__ rden, int B, int reps)
{
    const int s = (blockIdx.x << 2) + (threadIdx.x >> 6);
    if (s >= B) return;
    const int lane = threadIdx.x & 63;
    const int h  = lane >> 5;
    const int j  = lane & 31;
    const bool jact = (j < NK3);
    const int jc = jact ? j : 0;

    for (int rep = 0; rep < reps; ++rep) {
        const int start = ptr[s];
        const int end   = ptr[s + 1];

        const int wlo = (start + 15) >> 4;
        const int whi = end >> 4;
        const int head_end = min(wlo << 4, end);
        const int tail_beg = max(whi << 4, head_end);

        float acc = 0.0f;

        for (int w = wlo + h; w < whi; w += 2)
            acc += wp16[(size_t)w * NK3 + jc];

        for (int n = start + h; n < head_end; n += 2) {
            const float E = hw_exp2(x[n] * 1.44269504f);
            const float uv = uniforms[(size_t)n * NK3 + jc];
            acc = fmaf(E, hw_rcp(-hw_log2(uv)), acc);
        }
        for (int n = tail_beg + h; n < end; n += 2) {
            const float E = hw_exp2(x[n] * 1.44269504f);
            const float uv = uniforms[(size_t)n * NK3 + jc];
            acc = fmaf(E, hw_rcp(-hw_log2(uv)), acc);
        }

        acc += __shfl_xor(acc, 32, 64);

        if (h == 0 && jact) rden[(size_t)s * NK3 + j] = hw_rcp(acc);
    }
}

// ---------------- K3 (x reps) ----------------
__global__ __launch_bounds__(256) void k3_output(
    const float* __restrict__ x, const float* __restrict__ uniforms,
    const int* __restrict__ ptr, const float* __restrict__ rden,
    float* __restrict__ out, int N, int B, int reps)
{
    const int wid  = (blockIdx.x << 2) + (threadIdx.x >> 6);
    const int lane = threadIdx.x & 63;
    const int n = (wid << 6) + lane;
    if (n >= N) return;

    for (int rep = 0; rep < reps; ++rep) {
        int lo = 0, hi = B;
        while (hi - lo > 1) { int mid = (lo + hi) >> 1; if (ptr[mid] <= n) lo = mid; else hi = mid; }
        const int seg = lo;

        const float2* row = reinterpret_cast<const float2*>(uniforms + (size_t)n * NK3);
        const float2* lr  = reinterpret_cast<const float2*>(rden + (size_t)seg * NK3);

        float2 u[NKP], l[NKP];
#pragma unroll
        for (int k = 0; k < NKP; ++k) u[k] = row[k];
#pragma unroll
        for (int k = 0; k < NKP; ++k) l[k] = lr[k];

        float mx = 0.0f;
#pragma unroll
        for (int k = 0; k < NKP; ++k) {
            const float r0 = hw_rcp(-hw_log2(u[k].x));
            const float r1 = hw_rcp(-hw_log2(u[k].y));
            mx = fmaxf(mx, fmaxf(r0 * l[k].x, r1 * l[k].y));
        }
        out[n] = hw_exp2(x[n] * 1.44269504f) * mx;
    }
}

// ---------------- Fallback (unchanged) ----------------
__global__ __launch_bounds__(256) void gnn_fallback(
    const float* __restrict__ x, const float* __restrict__ uniforms,
    const int* __restrict__ ptr, float* __restrict__ out)
{
    const int wave = threadIdx.x >> 6;
    const int lane = threadIdx.x & 63;
    const int g = (blockIdx.x << 2) + wave;
    const int start = ptr[g];
    const int end   = ptr[g + 1];
    if (end <= start) return;

    float acc[NK3];
#pragma unroll
    for (int j = 0; j < NK3; ++j) acc[j] = 0.0f;
    const int iters = (end - start + 63) >> 6;

    for (int it = 0; it < iters; ++it) {
        const int n = start + (it << 6) + lane;
        if (n < end) {
            const float E = hw_exp2(x[n] * 1.44269504f);
            const float2* row = reinterpret_cast<const float2*>(uniforms + (size_t)n * NK3);
#pragma unroll
            for (int k = 0; k < NKP; ++k) {
                float2 u = row[k];
                acc[2 * k]     = fmaf(E, hw_rcp(-hw_log2(u.x)), acc[2 * k]);
                acc[2 * k + 1] = fmaf(E, hw_rcp(-hw_log2(u.y)), acc[2 * k + 1]);
            }
        }
    }
#pragma unroll
    for (int j = 0; j < NK3; ++j) {
        float v = acc[j];
#pragma unroll
        for (int off = 1; off < 64; off <<= 1) v += __shfl_xor(v, off, 64);
        acc[j] = hw_rcp(v);
    }
    for (int it = 0; it < iters; ++it) {
        const int n = start + (it << 6) + lane;
        if (n < end) {
            const float2* row = reinterpret_cast<const float2*>(uniforms + (size_t)n * NK3);
            float mx = 0.0f;
#pragma unroll
            for (int k = 0; k < NKP; ++k) {
                float2 u = row[k];
                const float r0 = hw_rcp(-hw_log2(u.x));
                const float r1 = hw_rcp(-hw_log2(u.y));
                mx = fmaxf(mx, fmaxf(r0 * acc[2 * k], r1 * acc[2 * k + 1]));
            }
            out[n] = hw_exp2(x[n] * 1.44269504f) * mx;
        }
    }
}

extern "C" void kernel_launch(void* const* d_in, const int* in_sizes, int n_in,
                              void* d_out, int out_size, void* d_ws, size_t ws_size,
                              hipStream_t stream) {
    const float* x        = (const float*)d_in[0];
    const float* uniforms = (const float*)d_in[1];
    const int*   ptr      = (const int*)d_in[2];
    float* out = (float*)d_out;

    const int N = in_sizes[0];
    const int B = in_sizes[2] - 1;
    const int NW16 = (N + 15) / 16;
    const size_t ws_needed = ((size_t)NW16 + (size_t)B) * NK3 * sizeof(float);

    const int REPS = 10;   // measurement round

    if (ws_size >= ws_needed && d_ws != nullptr) {
        float* wp16 = (float*)d_ws;
        float* rden = wp16 + (size_t)NW16 * NK3;

        const int NW64 = (N + 63) / 64;
        const int b1 = (NW64 + 3) / 4;
        k1_window_sums<<<b1, 256, 0, stream>>>(x, uniforms, wp16, N, REPS);

        const int b2 = (B + 3) / 4;
        k2_segment_den<<<b2, 256, 0, stream>>>(x, uniforms, ptr, wp16, rden, B, REPS);

        const int b3 = (NW64 + 3) / 4;
        k3_output<<<b3, 256, 0, stream>>>(x, uniforms, ptr, rden, out, N, B, REPS);
    } else {
        const int blocks = (B + 3) / 4;
        gnn_fallback<<<blocks, 256, 0, stream>>>(x, uniforms, ptr, out);
    }
}

// Round 15
// 71.560 us; speedup vs baseline: 2.5741x; 2.5741x over previous
//
#include <hip/hip_runtime.h>

#define NK3 30  // 3*K columns per node
#define NKP 15  // float2 pairs per row

__device__ __forceinline__ float hw_log2(float a) { return __builtin_amdgcn_logf(a); }
__device__ __forceinline__ float hw_exp2(float a) { return __builtin_amdgcn_exp2f(a); }
__device__ __forceinline__ float hw_rcp(float a)  { return __builtin_amdgcn_rcpf(a); }

// v += dpp(v): full-rate VALU cross-lane add (no DS ops).
template <int CTRL>
__device__ __forceinline__ float dpp_add(float v) {
    int s = __builtin_amdgcn_update_dpp(0, __float_as_int(v), CTRL, 0xF, 0xF, true);
    return v + __int_as_float(s);
}
// 16-lane group sum (every lane ends with the group sum) — HW-verified r10-14.
__device__ __forceinline__ float group16_sum(float v) {
    v = dpp_add<0xB1>(v);    // quad_perm [1,0,3,2]
    v = dpp_add<0x4E>(v);    // quad_perm [2,3,0,1]
    v = dpp_add<0x141>(v);   // ROW_HALF_MIRROR
    v = dpp_add<0x140>(v);   // ROW_MIRROR
    return v;
}

// Math: e_nj = exp(x_n + gumbel_nj) = exp2(x_n*log2e) * rcp(-log2 u_nj) * (1/ln2)
//       [1/ln2 cancels in the probs ratio]
// den_j = sum_n exp2(xe_n)*rcp(w_nj);  out = exp2(xe)*max_j(r_j * rcp(den_j)).
//
// Measured (r14 reps=10 isolation): k1 ~8.3us, k2 ~1.5us, k3 ~8.3us.
// dur_us is floored at ~70us by the harness's per-replay 480MiB d_ws poison
// fill (runs at 90% HBM peak); the whole chain hides under it.

// ---------------- K1: 16-node partial sums. 1 window (64 nodes) per wave. ----------------
__global__ __launch_bounds__(256) void k1_window_sums(
    const float* __restrict__ x, const float* __restrict__ uniforms,
    float* __restrict__ wp16, int N)
{
    const int w    = (blockIdx.x << 2) + (threadIdx.x >> 6);  // 64-node window id
    const int lane = threadIdx.x & 63;
    const int base = w << 6;
    if (base >= N) return;

    const int n  = base + lane;
    const int nv = (n < N) ? n : (N - 1);

    const float2* row = reinterpret_cast<const float2*>(uniforms + (size_t)nv * NK3);
    float2 u[NKP];
#pragma unroll
    for (int k = 0; k < NKP; ++k) u[k] = row[k];
    float E = hw_exp2(x[nv] * 1.44269504f);
    E = (n < N) ? E : 0.0f;   // defensive; N%64==0 here

    float r[NK3];
#pragma unroll
    for (int k = 0; k < NKP; ++k) {
        r[2 * k]     = E * hw_rcp(-hw_log2(u[k].x));
        r[2 * k + 1] = E * hw_rcp(-hw_log2(u[k].y));
    }

#pragma unroll
    for (int j = 0; j < NK3; ++j) r[j] = group16_sum(r[j]);

    if ((lane & 15) == 0) {   // 4 group leaders store 16-node partials
        float* dst = wp16 + ((size_t)(base >> 4) + (lane >> 4)) * NK3;
#pragma unroll
        for (int j = 0; j < NK3; ++j) dst[j] = r[j];
    }
}

// ---------------- K2: per-segment RECIPROCAL denominators ----------------
// One wave per segment. lane = h*32 + j. Stores rcp(den) so k3 just multiplies.
__global__ __launch_bounds__(256) void k2_segment_den(
    const float* __restrict__ x, const float* __restrict__ uniforms,
    const int* __restrict__ ptr, const float* __restrict__ wp16,
    float* __restrict__ rden, int B)
{
    const int s = (blockIdx.x << 2) + (threadIdx.x >> 6);
    if (s >= B) return;
    const int lane = threadIdx.x & 63;
    const int h  = lane >> 5;
    const int j  = lane & 31;
    const bool jact = (j < NK3);
    const int jc = jact ? j : 0;

    const int start = ptr[s];
    const int end   = ptr[s + 1];

    const int wlo = (start + 15) >> 4;   // first full 16-window
    const int whi = end >> 4;            // one past last full 16-window
    const int head_end = min(wlo << 4, end);
    const int tail_beg = max(whi << 4, head_end);

    float acc = 0.0f;

    // full 16-node windows, interleaved by h (coalesced 120B rows)
    for (int w = wlo + h; w < whi; w += 2)
        acc += wp16[(size_t)w * NK3 + jc];

    // head edge [start, head_end): <=15 nodes
    for (int n = start + h; n < head_end; n += 2) {
        const float E = hw_exp2(x[n] * 1.44269504f);
        const float uv = uniforms[(size_t)n * NK3 + jc];
        acc = fmaf(E, hw_rcp(-hw_log2(uv)), acc);
    }
    // tail edge [tail_beg, end): <=15 nodes
    for (int n = tail_beg + h; n < end; n += 2) {
        const float E = hw_exp2(x[n] * 1.44269504f);
        const float uv = uniforms[(size_t)n * NK3 + jc];
        acc = fmaf(E, hw_rcp(-hw_log2(uv)), acc);
    }

    acc += __shfl_xor(acc, 32, 64);      // combine even/odd halves

    if (h == 0 && jact) rden[(size_t)s * NK3 + j] = hw_rcp(acc);  // coalesced
}

// ---------------- K3: out[n] = exp2(xe) * max_j (r_j * rden_j) ----------------
// 64 nodes per wave, row-per-lane, rden pre-inverted.
__global__ __launch_bounds__(256) void k3_output(
    const float* __restrict__ x, const float* __restrict__ uniforms,
    const int* __restrict__ ptr, const float* __restrict__ rden,
    float* __restrict__ out, int N, int B)
{
    const int wid  = (blockIdx.x << 2) + (threadIdx.x >> 6);
    const int lane = threadIdx.x & 63;
    const int n = (wid << 6) + lane;
    if (n >= N) return;

    // per-lane segment via binary search (ptr L1/L2-hot)
    int lo = 0, hi = B;
    while (hi - lo > 1) { int mid = (lo + hi) >> 1; if (ptr[mid] <= n) lo = mid; else hi = mid; }
    const int seg = lo;

    const float2* row = reinterpret_cast<const float2*>(uniforms + (size_t)n * NK3);
    const float2* lr  = reinterpret_cast<const float2*>(rden + (size_t)seg * NK3);

    float2 u[NKP], l[NKP];
#pragma unroll
    for (int k = 0; k < NKP; ++k) u[k] = row[k];
#pragma unroll
    for (int k = 0; k < NKP; ++k) l[k] = lr[k];

    float mx = 0.0f;
#pragma unroll
    for (int k = 0; k < NKP; ++k) {
        const float r0 = hw_rcp(-hw_log2(u[k].x));
        const float r1 = hw_rcp(-hw_log2(u[k].y));
        mx = fmaxf(mx, fmaxf(r0 * l[k].x, r1 * l[k].y));
    }
    out[n] = hw_exp2(x[n] * 1.44269504f) * mx;
}

// ---------------- Fallback: single kernel (if ws too small) ----------------
__global__ __launch_bounds__(256) void gnn_fallback(
    const float* __restrict__ x, const float* __restrict__ uniforms,
    const int* __restrict__ ptr, float* __restrict__ out)
{
    const int wave = threadIdx.x >> 6;
    const int lane = threadIdx.x & 63;
    const int g = (blockIdx.x << 2) + wave;
    const int start = ptr[g];
    const int end   = ptr[g + 1];
    if (end <= start) return;

    float acc[NK3];
#pragma unroll
    for (int j = 0; j < NK3; ++j) acc[j] = 0.0f;
    const int iters = (end - start + 63) >> 6;

    for (int it = 0; it < iters; ++it) {
        const int n = start + (it << 6) + lane;
        if (n < end) {
            const float E = hw_exp2(x[n] * 1.44269504f);
            const float2* row = reinterpret_cast<const float2*>(uniforms + (size_t)n * NK3);
#pragma unroll
            for (int k = 0; k < NKP; ++k) {
                float2 u = row[k];
                acc[2 * k]     = fmaf(E, hw_rcp(-hw_log2(u.x)), acc[2 * k]);
                acc[2 * k + 1] = fmaf(E, hw_rcp(-hw_log2(u.y)), acc[2 * k + 1]);
            }
        }
    }
#pragma unroll
    for (int j = 0; j < NK3; ++j) {
        float v = acc[j];
#pragma unroll
        for (int off = 1; off < 64; off <<= 1) v += __shfl_xor(v, off, 64);
        acc[j] = hw_rcp(v);
    }
    for (int it = 0; it < iters; ++it) {
        const int n = start + (it << 6) + lane;
        if (n < end) {
            const float2* row = reinterpret_cast<const float2*>(uniforms + (size_t)n * NK3);
            float mx = 0.0f;
#pragma unroll
            for (int k = 0; k < NKP; ++k) {
                float2 u = row[k];
                const float r0 = hw_rcp(-hw_log2(u.x));
                const float r1 = hw_rcp(-hw_log2(u.y));
                mx = fmaxf(mx, fmaxf(r0 * acc[2 * k], r1 * acc[2 * k + 1]));
            }
            out[n] = hw_exp2(x[n] * 1.44269504f) * mx;
        }
    }
}

extern "C" void kernel_launch(void* const* d_in, const int* in_sizes, int n_in,
                              void* d_out, int out_size, void* d_ws, size_t ws_size,
                              hipStream_t stream) {
    const float* x        = (const float*)d_in[0];
    const float* uniforms = (const float*)d_in[1];
    const int*   ptr      = (const int*)d_in[2];
    float* out = (float*)d_out;

    const int N = in_sizes[0];
    const int B = in_sizes[2] - 1;
    const int NW16 = (N + 15) / 16;                   // 16-node windows
    const size_t ws_needed = ((size_t)NW16 + (size_t)B) * NK3 * sizeof(float);

    if (ws_size >= ws_needed && d_ws != nullptr) {
        float* wp16 = (float*)d_ws;                   // [NW16][30]
        float* rden = wp16 + (size_t)NW16 * NK3;      // [B][30]

        const int NW64 = (N + 63) / 64;
        const int b1 = (NW64 + 3) / 4;                // 1 window / wave
        k1_window_sums<<<b1, 256, 0, stream>>>(x, uniforms, wp16, N);

        const int b2 = (B + 3) / 4;                   // 1 segment / wave
        k2_segment_den<<<b2, 256, 0, stream>>>(x, uniforms, ptr, wp16, rden, B);

        const int b3 = (NW64 + 3) / 4;                // 64 nodes / wave
        k3_output<<<b3, 256, 0, stream>>>(x, uniforms, ptr, rden, out, N, B);
    } else {
        const int blocks = (B + 3) / 4;
        gnn_fallback<<<blocks, 256, 0, stream>>>(x, uniforms, ptr, out);
    }
}